// Round 10
// baseline (402.338 us; speedup 1.0000x reference)
//
#include <hip/hip_runtime.h>
#include <hip/hip_bf16.h>
#include <stdint.h>

#define BATCH 8
#define SEQ   4096
#define DM    512
#define HD    120
#define PH    2048   // p-range per attn block
#define NT    32     // tiles per pass (PH/64)

typedef __bf16   v8bf  __attribute__((ext_vector_type(8)));
typedef float    v4f   __attribute__((ext_vector_type(4)));
typedef int      i4    __attribute__((ext_vector_type(4)));
typedef uint32_t u32x2 __attribute__((ext_vector_type(2)));
typedef uint32_t u32x4 __attribute__((ext_vector_type(4)));
typedef float    f32x4 __attribute__((ext_vector_type(4)));

static __device__ __forceinline__ ushort f2bf(float x) {
  uint32_t u = __builtin_bit_cast(uint32_t, x);
  return (ushort)((u + 0x7fffu + ((u >> 16) & 1u)) >> 16);
}
static __device__ __forceinline__ float bf2f(ushort h) {
  return __builtin_bit_cast(float, (uint32_t)h << 16);
}

// -------------------------------------------------------------------------
// wsplit_kernel: w_q (120x512 f32) -> whi/wlo bf16 planes [128][512]
// (cols 120..127 zero). hi = bf16(w), lo = bf16(w - hi). 64 blocks x 256.
// -------------------------------------------------------------------------
__global__ __launch_bounds__(256) void wsplit_kernel(
    const float* __restrict__ wq, ushort* __restrict__ whi,
    ushort* __restrict__ wlo)
{
  int base = (blockIdx.x * 256 + threadIdx.x) * 4;
  #pragma unroll
  for (int j = 0; j < 4; ++j) {
    int e = base + j;                 // e = col*512 + k
    int col = e >> 9;
    float w = (col < HD) ? wq[e - (col << 9) + col * DM] : 0.f;
    ushort h = f2bf(w);
    whi[e] = h;
    wlo[e] = f2bf(w - bf2f(h));
  }
}

// -------------------------------------------------------------------------
// prep_kernel: 1024 blocks x 256 thr.
// EVEN blocks: ctx GEMM via split-bf16 MFMA (3 MFMAs: hh, hl, lh), 64 rows,
//   K tiled by 32, then bias+wt+L2-normalize and scatter-store bf16 ctx
//   PRE-SWIZZLED (byte-in-row = slot*16 ^ ((row&7)<<4)).
// ODD blocks: compress 64 mask rows -> bitsT[b][pw][q] (transposed via LDS).
// -------------------------------------------------------------------------
#define MFMA(A, B, C) __builtin_amdgcn_mfma_f32_16x16x32_bf16(A, B, C, 0, 0, 0)

__global__ __launch_bounds__(256) void prep_kernel(
    const float* __restrict__ q, const float* __restrict__ bq,
    const float* __restrict__ wt, const int* __restrict__ mask,
    const ushort* __restrict__ whi, const ushort* __restrict__ wlo,
    ushort* __restrict__ ctx, uint32_t* __restrict__ bitsT)
{
  __shared__ __align__(16) char smem[33024];
  const int t = threadIdx.x;

  if (blockIdx.x & 1) {
    // ---- mask compression, 64 rows, transposed output ----
    uint32_t (*bw)[129] = (uint32_t(*)[129])smem;  // [64][129]
    const int cb = blockIdx.x >> 1;                // 0..511
    const size_t row0 = (size_t)cb * 64;
    const int b     = (int)(row0 >> 12);
    const int qbase = (int)(row0 & 4095);
    const int rhalf = t >> 7, pw = t & 127;
    for (int s = 0; s < 32; ++s) {
      int row = s * 2 + rhalf;
      const int* mp = mask + (row0 + row) * SEQ + pw * 32;
      uint32_t wd = 0;
      #pragma unroll
      for (int k = 0; k < 8; ++k) {
        i4 m = *(const i4*)(mp + k * 4);
        wd |= (uint32_t)(m.x != 0) << (k * 4);
        wd |= (uint32_t)(m.y != 0) << (k * 4 + 1);
        wd |= (uint32_t)(m.z != 0) << (k * 4 + 2);
        wd |= (uint32_t)(m.w != 0) << (k * 4 + 3);
      }
      bw[row][pw] = wd;
    }
    __syncthreads();
    const int qq = t & 63, pg = t >> 6;            // 4 pw-groups x 64 q
    uint32_t* bT = bitsT + (size_t)b * 128 * 4096 + qbase + qq;
    #pragma unroll 8
    for (int i = 0; i < 32; ++i) {
      int pw2 = pg * 32 + i;
      bT[(size_t)pw2 * 4096] = bw[qq][pw2];
    }
    return;
  }

  // ---- ctx GEMM via MFMA, 64 rows ----
  // LDS (bf16, rows padded to 40 elems = 80 B, 16B-aligned, ~2-way banks):
  ushort* AHI = (ushort*)smem;          // [64][40]  5120 B
  ushort* ALO = AHI + 64 * 40;          //           5120 B
  ushort* BHI = ALO + 64 * 40;          // [128][40] 10240 B
  ushort* BLO = BHI + 128 * 40;         //           10240 B -> 30720 total

  const int gb = blockIdx.x >> 1;       // 0..511
  const size_t row0 = (size_t)gb * 64;
  const int w = t >> 6, lane = t & 63;
  const int ln = lane & 15, g = lane >> 4;

  v4f acc[8];
  #pragma unroll
  for (int c = 0; c < 8; ++c) acc[c] = (v4f){0.f, 0.f, 0.f, 0.f};

  const int srow = t >> 2, sk0 = (t & 3) * 8;      // A staging map
  const int bcol = t & 127, bpl = t >> 7;          // B staging map
  const ushort* bsrc = (bpl ? wlo : whi) + bcol * DM;
  ushort* bdst = (bpl ? BLO : BHI) + bcol * 40;

  for (int kc = 0; kc < 16; ++kc) {
    __syncthreads();
    {  // stage A: 64 rows x 32 k f32 -> hi/lo bf16
      f32x4 v0 = *(const f32x4*)&q[(row0 + srow) * DM + kc * 32 + sk0];
      f32x4 v1 = *(const f32x4*)&q[(row0 + srow) * DM + kc * 32 + sk0 + 4];
      ushort h[8], l[8];
      #pragma unroll
      for (int i = 0; i < 4; ++i) {
        h[i] = f2bf(v0[i]); l[i] = f2bf(v0[i] - bf2f(h[i]));
        h[4 + i] = f2bf(v1[i]); l[4 + i] = f2bf(v1[i] - bf2f(h[4 + i]));
      }
      u32x4 ph, pl;
      #pragma unroll
      for (int i = 0; i < 4; ++i) {
        ph[i] = (uint32_t)h[2 * i] | ((uint32_t)h[2 * i + 1] << 16);
        pl[i] = (uint32_t)l[2 * i] | ((uint32_t)l[2 * i + 1] << 16);
      }
      *(u32x4*)&AHI[srow * 40 + sk0] = ph;
      *(u32x4*)&ALO[srow * 40 + sk0] = pl;
    }
    {  // stage B: 128 cols x 32 k, both planes, from presplit global
      const ushort* s = bsrc + kc * 32;
      *(u32x4*)&bdst[0]  = *(const u32x4*)&s[0];
      *(u32x4*)&bdst[8]  = *(const u32x4*)&s[8];
      *(u32x4*)&bdst[16] = *(const u32x4*)&s[16];
      *(u32x4*)&bdst[24] = *(const u32x4*)&s[24];
    }
    __syncthreads();

    v8bf ah = *(const v8bf*)&AHI[(w * 16 + ln) * 40 + g * 8];
    v8bf al = *(const v8bf*)&ALO[(w * 16 + ln) * 40 + g * 8];
    #pragma unroll
    for (int c = 0; c < 8; ++c) {
      v8bf bh = *(const v8bf*)&BHI[(c * 16 + ln) * 40 + g * 8];
      v8bf bl = *(const v8bf*)&BLO[(c * 16 + ln) * 40 + g * 8];
      acc[c] = MFMA(ah, bh, acc[c]);
      acc[c] = MFMA(ah, bl, acc[c]);
      acc[c] = MFMA(al, bh, acc[c]);
    }
  }

  // epilogue: lane holds rows w*16+g*4+i (i 0..3), cols c*16+ln (c 0..7)
  float wtv[8], bqv[8];
  #pragma unroll
  for (int c = 0; c < 8; ++c) {
    int col = c * 16 + ln;
    wtv[c] = (col < HD) ? wt[col] : 0.f;
    bqv[c] = (col < HD) ? bq[col] : 0.f;
  }
  #pragma unroll
  for (int i = 0; i < 4; ++i) {
    int row = w * 16 + g * 4 + i;
    float v[8]; float ss = 0.f;
    #pragma unroll
    for (int c = 0; c < 8; ++c) {
      v[c] = (acc[c][i] + bqv[c]) * wtv[c];
      ss = fmaf(v[c], v[c], ss);
    }
    ss += __shfl_xor(ss, 1, 64);
    ss += __shfl_xor(ss, 2, 64);
    ss += __shfl_xor(ss, 4, 64);
    ss += __shfl_xor(ss, 8, 64);
    float rinv = 1.f / fmaxf(sqrtf(ss), 1e-12f);
    char* rbase = (char*)ctx + (row0 + row) * 256;
    int rx = (row & 7) << 4;
    #pragma unroll
    for (int c = 0; c < 8; ++c) {
      int col = c * 16 + ln;
      *(ushort*)(rbase + (((col >> 3) * 16) ^ rx) + (col & 7) * 2)
          = f2bf(v[c] * rinv);
    }
  }
}

// -------------------------------------------------------------------------
// attn: unchanged from R9 (passed). Block = 64 q x 2048 p, 1024 blocks,
// 4 waves, reg-staged double-buffered LDS tile, BAR = lgkmcnt(0)+s_barrier,
// 16x16x32 MFMA transposed D[p][q], fixed softmax max = 1.0.
// -------------------------------------------------------------------------
static __device__ __forceinline__ v8bf ldfrag(const char* base, int row, int slot) {
  int byte = row * 256 + ((slot * 16) ^ ((row & 7) << 4));
  return __builtin_bit_cast(v8bf, *(const u32x4*)(base + byte));
}

#define STG_LOAD(R, j) do {                                                   \
  const char* _g = ctxb + (size_t)(P0 + (j) * 64) * 256 + w * 4096 + lane * 16;\
  R##0 = *(const u32x4*)(_g);        R##1 = *(const u32x4*)(_g + 1024);       \
  R##2 = *(const u32x4*)(_g + 2048); R##3 = *(const u32x4*)(_g + 3072);       \
} while (0)

#define STG_WRITE(R, buf) do {                                                \
  char* _l = (buf) + w * 4096 + lane * 16;                                    \
  *(u32x4*)(_l)        = R##0;  *(u32x4*)(_l + 1024) = R##1;                  \
  *(u32x4*)(_l + 2048) = R##2;  *(u32x4*)(_l + 3072) = R##3;                  \
} while (0)

#define QKT(buf, acc) do {                                                    \
  _Pragma("unroll")                                                           \
  for (int _t = 0; _t < 4; ++_t) {                                            \
    acc[_t] = (v4f){0.f, 0.f, 0.f, 0.f};                                      \
    _Pragma("unroll")                                                         \
    for (int _k = 0; _k < 4; ++_k) {                                          \
      v8bf _a = ldfrag(buf, _t * 16 + ln, _k * 4 + g);                        \
      acc[_t] = MFMA(_a, qf[_k], acc[_t]);                                    \
    }                                                                         \
  }                                                                           \
} while (0)

#define LDB(x, y, tj) do {                                                    \
  x = btb[(size_t)(tj) * 2 * 4096];                                           \
  y = btb[((size_t)(tj) * 2 + 1) * 4096];                                     \
} while (0)

#define EPIA() do {                                                           \
  _Pragma("unroll")                                                           \
  for (int _t2 = 0; _t2 < 4; ++_t2) {                                         \
    uint32_t nib = ((_t2 < 2 ? bcx : bcy) >> ((_t2 & 1) * 16 + g * 4));       \
    _Pragma("unroll")                                                         \
    for (int _i = 0; _i < 4; ++_i) {                                          \
      float e = __expf(acc[_t2][_i] - 1.0f);                                  \
      lsum += ((nib >> _i) & 1u) ? e : 0.f;                                   \
    }                                                                         \
  }                                                                           \
} while (0)

#define EPIB(tj) do {                                                         \
  _Pragma("unroll")                                                           \
  for (int _t2 = 0; _t2 < 4; ++_t2) {                                         \
    uint32_t nib = ((_t2 < 2 ? bcx : bcy) >> ((_t2 & 1) * 16 + g * 4));       \
    f32x4 o;                                                                  \
    _Pragma("unroll")                                                         \
    for (int _i = 0; _i < 4; ++_i)                                            \
      o[_i] = ((nib >> _i) & 1u) ? __expf(acc[_t2][_i] - 1.0f) * lir : 0.f;   \
    *(f32x4*)(orow + (size_t)(tj) * 64 + _t2 * 16 + g * 4) = o;               \
  }                                                                           \
} while (0)

#define BAR() do {                                                            \
  asm volatile("s_waitcnt lgkmcnt(0)" ::: "memory");                          \
  __builtin_amdgcn_s_barrier();                                               \
  __builtin_amdgcn_sched_barrier(0);                                          \
} while (0)

#define ATTN_COMMON                                                           \
  __shared__ __align__(16) char lds[32768];                                   \
  char* B0 = lds;                                                             \
  char* B1 = lds + 16384;                                                     \
  const int t    = threadIdx.x;                                               \
  const int b    = blockIdx.x & 7;                                            \
  const int rest = blockIdx.x >> 3;                                           \
  const int ph   = rest & 1;                                                  \
  const int qg   = rest >> 1;                                                 \
  const int w    = t >> 6, lane = t & 63;                                     \
  const int ln   = lane & 15, g = lane >> 4;                                  \
  const int q0   = qg * 64;                                                   \
  const int P0   = ph * PH;                                                   \
  const int qrow = q0 + w * 16 + ln;                                          \
  const char* ctxb = (const char*)ctx + (size_t)b * SEQ * 256;                \
  const uint32_t* __restrict__ btb =                                          \
      bitsT + ((size_t)b * 128 + (P0 >> 5)) * 4096 + qrow;                    \
  v8bf qf[4];                                                                 \
  _Pragma("unroll")                                                           \
  for (int kk = 0; kk < 4; ++kk) {                                            \
    int slot = kk * 4 + g;                                                    \
    qf[kk] = *(const v8bf*)(ctxb + (size_t)qrow * 256 +                       \
                            ((slot * 16) ^ ((qrow & 7) << 4)));               \
  }                                                                           \
  u32x4 sA0, sA1, sA2, sA3, sB0, sB1, sB2, sB3;                               \
  uint32_t bcx, bcy, bnx = 0, bny = 0;

__global__ __launch_bounds__(256) void attnA_kernel(
    const ushort* __restrict__ ctx, const uint32_t* __restrict__ bitsT,
    float* __restrict__ lpart)
{
  ATTN_COMMON
  float lsum = 0.f;

  STG_LOAD(sA, 0);
  STG_WRITE(sA, B0);
  STG_LOAD(sB, 1);
  LDB(bcx, bcy, 0);
  __syncthreads();

  for (int jj = 0; jj < NT; jj += 2) {
    if (jj + 1 < NT) LDB(bnx, bny, jj + 1);
    if (jj + 2 < NT) STG_LOAD(sA, jj + 2);
    { v4f acc[4]; QKT(B0, acc); STG_WRITE(sB, B1); EPIA(); }
    BAR();
    bcx = bnx; bcy = bny;

    if (jj + 2 < NT) LDB(bnx, bny, jj + 2);
    if (jj + 3 < NT) STG_LOAD(sB, jj + 3);
    { v4f acc[4]; QKT(B1, acc); if (jj + 2 < NT) STG_WRITE(sA, B0); EPIA(); }
    BAR();
    bcx = bnx; bcy = bny;
  }

  lsum += __shfl_xor(lsum, 16, 64);
  lsum += __shfl_xor(lsum, 32, 64);
  if (g == 0)
    lpart[(size_t)ph * (BATCH * SEQ) + (size_t)b * SEQ + qrow] = lsum;
}

__global__ __launch_bounds__(256) void attnB_kernel(
    const ushort* __restrict__ ctx, const uint32_t* __restrict__ bitsT,
    const float* __restrict__ lpart, float* __restrict__ out)
{
  ATTN_COMMON
  const size_t grow = (size_t)b * SEQ + qrow;
  const float lf = lpart[grow] + lpart[(size_t)(BATCH * SEQ) + grow];
  const float lir = (lf > 0.f) ? (1.f / lf) : 0.f;
  float* __restrict__ orow = out + grow * SEQ + P0;

  STG_LOAD(sA, 0);
  STG_WRITE(sA, B0);
  STG_LOAD(sB, 1);
  LDB(bcx, bcy, 0);
  __syncthreads();

  for (int jj = 0; jj < NT; jj += 2) {
    if (jj + 1 < NT) LDB(bnx, bny, jj + 1);
    if (jj + 2 < NT) STG_LOAD(sA, jj + 2);
    { v4f acc[4]; QKT(B0, acc); STG_WRITE(sB, B1); EPIB(jj); }
    BAR();
    bcx = bnx; bcy = bny;

    if (jj + 2 < NT) LDB(bnx, bny, jj + 2);
    if (jj + 3 < NT) STG_LOAD(sB, jj + 3);
    { v4f acc[4]; QKT(B1, acc); if (jj + 2 < NT) STG_WRITE(sA, B0); EPIB(jj + 1); }
    BAR();
    bcx = bnx; bcy = bny;
  }
}

// -------------------------------------------------------------------------
extern "C" void kernel_launch(void* const* d_in, const int* in_sizes, int n_in,
                              void* d_out, int out_size, void* d_ws, size_t ws_size,
                              hipStream_t stream) {
  const float* query = (const float*)d_in[0];
  const int*   mask  = (const int*)d_in[1];
  const float* w_q   = (const float*)d_in[2];
  const float* b_q   = (const float*)d_in[3];
  const float* wt    = (const float*)d_in[4];
  float* out = (float*)d_out;

  ushort*   ctx   = (ushort*)d_ws;                               // 8 MB @0
  ushort*   whi   = (ushort*)((char*)d_ws + (8u << 20));         // 128 KB
  ushort*   wlo   = (ushort*)((char*)d_ws + (8u << 20) + (128u << 10));
  uint32_t* bitsT = (uint32_t*)((char*)d_ws + (9u << 20));       // 16.78 MB
  float*    lpart = (float*)((char*)d_ws + (26u << 20));         // 256 KB

  wsplit_kernel<<<dim3(64),   dim3(256), 0, stream>>>(w_q, whi, wlo);
  prep_kernel  <<<dim3(1024), dim3(256), 0, stream>>>(query, b_q, wt, mask,
                                                      whi, wlo, ctx, bitsT);
  attnA_kernel <<<dim3(1024), dim3(256), 0, stream>>>(ctx, bitsT, lpart);
  attnB_kernel <<<dim3(1024), dim3(256), 0, stream>>>(ctx, bitsT, lpart, out);
}

// Round 11
// 399.901 us; speedup vs baseline: 1.0061x; 1.0061x over previous
//
#include <hip/hip_runtime.h>
#include <hip/hip_bf16.h>
#include <stdint.h>

#define BATCH 8
#define SEQ   4096
#define DM    512
#define HD    120
#define PH    2048   // p-range per attn block
#define NT    32     // tiles per pass (PH/64)

typedef __bf16   v8bf  __attribute__((ext_vector_type(8)));
typedef float    v4f   __attribute__((ext_vector_type(4)));
typedef int      i4    __attribute__((ext_vector_type(4)));
typedef uint32_t u32x2 __attribute__((ext_vector_type(2)));
typedef uint32_t u32x4 __attribute__((ext_vector_type(4)));
typedef float    f32x4 __attribute__((ext_vector_type(4)));

static __device__ __forceinline__ ushort f2bf(float x) {
  uint32_t u = __builtin_bit_cast(uint32_t, x);
  return (ushort)((u + 0x7fffu + ((u >> 16) & 1u)) >> 16);
}
static __device__ __forceinline__ float bf2f(ushort h) {
  return __builtin_bit_cast(float, (uint32_t)h << 16);
}

// -------------------------------------------------------------------------
// wsplit_kernel: w_q (120x512 f32) -> whi/wlo bf16 planes [128][512].
// -------------------------------------------------------------------------
__global__ __launch_bounds__(256) void wsplit_kernel(
    const float* __restrict__ wq, ushort* __restrict__ whi,
    ushort* __restrict__ wlo)
{
  int base = (blockIdx.x * 256 + threadIdx.x) * 4;
  #pragma unroll
  for (int j = 0; j < 4; ++j) {
    int e = base + j;                 // e = col*512 + k
    int col = e >> 9;
    float w = (col < HD) ? wq[e - (col << 9) + col * DM] : 0.f;
    ushort h = f2bf(w);
    whi[e] = h;
    wlo[e] = f2bf(w - bf2f(h));
  }
}

// -------------------------------------------------------------------------
// prep_kernel: 1024 blocks. EVEN: ctx GEMM via split-bf16 MFMA, store bf16
// ctx PRE-SWIZZLED with slot' = slot ^ (row & 15). ODD: mask -> bitsT[b][pw][q].
// -------------------------------------------------------------------------
#define MFMA(A, B, C) __builtin_amdgcn_mfma_f32_16x16x32_bf16(A, B, C, 0, 0, 0)

__global__ __launch_bounds__(256) void prep_kernel(
    const float* __restrict__ q, const float* __restrict__ bq,
    const float* __restrict__ wt, const int* __restrict__ mask,
    const ushort* __restrict__ whi, const ushort* __restrict__ wlo,
    ushort* __restrict__ ctx, uint32_t* __restrict__ bitsT)
{
  __shared__ __align__(16) char smem[33024];
  const int t = threadIdx.x;

  if (blockIdx.x & 1) {
    uint32_t (*bw)[129] = (uint32_t(*)[129])smem;  // [64][129]
    const int cb = blockIdx.x >> 1;
    const size_t row0 = (size_t)cb * 64;
    const int b     = (int)(row0 >> 12);
    const int qbase = (int)(row0 & 4095);
    const int rhalf = t >> 7, pw = t & 127;
    for (int s = 0; s < 32; ++s) {
      int row = s * 2 + rhalf;
      const int* mp = mask + (row0 + row) * SEQ + pw * 32;
      uint32_t wd = 0;
      #pragma unroll
      for (int k = 0; k < 8; ++k) {
        i4 m = *(const i4*)(mp + k * 4);
        wd |= (uint32_t)(m.x != 0) << (k * 4);
        wd |= (uint32_t)(m.y != 0) << (k * 4 + 1);
        wd |= (uint32_t)(m.z != 0) << (k * 4 + 2);
        wd |= (uint32_t)(m.w != 0) << (k * 4 + 3);
      }
      bw[row][pw] = wd;
    }
    __syncthreads();
    const int qq = t & 63, pg = t >> 6;
    uint32_t* bT = bitsT + (size_t)b * 128 * 4096 + qbase + qq;
    #pragma unroll 8
    for (int i = 0; i < 32; ++i) {
      int pw2 = pg * 32 + i;
      bT[(size_t)pw2 * 4096] = bw[qq][pw2];
    }
    return;
  }

  // ---- ctx GEMM via MFMA ----
  ushort* AHI = (ushort*)smem;
  ushort* ALO = AHI + 64 * 40;
  ushort* BHI = ALO + 64 * 40;
  ushort* BLO = BHI + 128 * 40;

  const int gb = blockIdx.x >> 1;
  const size_t row0 = (size_t)gb * 64;
  const int w = t >> 6, lane = t & 63;
  const int ln = lane & 15, g = lane >> 4;

  v4f acc[8];
  #pragma unroll
  for (int c = 0; c < 8; ++c) acc[c] = (v4f){0.f, 0.f, 0.f, 0.f};

  const int srow = t >> 2, sk0 = (t & 3) * 8;
  const int bcol = t & 127, bpl = t >> 7;
  const ushort* bsrc = (bpl ? wlo : whi) + bcol * DM;
  ushort* bdst = (bpl ? BLO : BHI) + bcol * 40;

  for (int kc = 0; kc < 16; ++kc) {
    __syncthreads();
    {
      f32x4 v0 = *(const f32x4*)&q[(row0 + srow) * DM + kc * 32 + sk0];
      f32x4 v1 = *(const f32x4*)&q[(row0 + srow) * DM + kc * 32 + sk0 + 4];
      ushort h[8], l[8];
      #pragma unroll
      for (int i = 0; i < 4; ++i) {
        h[i] = f2bf(v0[i]); l[i] = f2bf(v0[i] - bf2f(h[i]));
        h[4 + i] = f2bf(v1[i]); l[4 + i] = f2bf(v1[i] - bf2f(h[4 + i]));
      }
      u32x4 ph, pl;
      #pragma unroll
      for (int i = 0; i < 4; ++i) {
        ph[i] = (uint32_t)h[2 * i] | ((uint32_t)h[2 * i + 1] << 16);
        pl[i] = (uint32_t)l[2 * i] | ((uint32_t)l[2 * i + 1] << 16);
      }
      *(u32x4*)&AHI[srow * 40 + sk0] = ph;
      *(u32x4*)&ALO[srow * 40 + sk0] = pl;
    }
    {
      const ushort* s = bsrc + kc * 32;
      *(u32x4*)&bdst[0]  = *(const u32x4*)&s[0];
      *(u32x4*)&bdst[8]  = *(const u32x4*)&s[8];
      *(u32x4*)&bdst[16] = *(const u32x4*)&s[16];
      *(u32x4*)&bdst[24] = *(const u32x4*)&s[24];
    }
    __syncthreads();

    v8bf ah = *(const v8bf*)&AHI[(w * 16 + ln) * 40 + g * 8];
    v8bf al = *(const v8bf*)&ALO[(w * 16 + ln) * 40 + g * 8];
    #pragma unroll
    for (int c = 0; c < 8; ++c) {
      v8bf bh = *(const v8bf*)&BHI[(c * 16 + ln) * 40 + g * 8];
      v8bf bl = *(const v8bf*)&BLO[(c * 16 + ln) * 40 + g * 8];
      acc[c] = MFMA(ah, bh, acc[c]);
      acc[c] = MFMA(ah, bl, acc[c]);
      acc[c] = MFMA(al, bh, acc[c]);
    }
  }

  float wtv[8], bqv[8];
  #pragma unroll
  for (int c = 0; c < 8; ++c) {
    int col = c * 16 + ln;
    wtv[c] = (col < HD) ? wt[col] : 0.f;
    bqv[c] = (col < HD) ? bq[col] : 0.f;
  }
  #pragma unroll
  for (int i = 0; i < 4; ++i) {
    int row = w * 16 + g * 4 + i;
    float v[8]; float ss = 0.f;
    #pragma unroll
    for (int c = 0; c < 8; ++c) {
      v[c] = (acc[c][i] + bqv[c]) * wtv[c];
      ss = fmaf(v[c], v[c], ss);
    }
    ss += __shfl_xor(ss, 1, 64);
    ss += __shfl_xor(ss, 2, 64);
    ss += __shfl_xor(ss, 4, 64);
    ss += __shfl_xor(ss, 8, 64);
    float rinv = 1.f / fmaxf(sqrtf(ss), 1e-12f);
    char* rbase = (char*)ctx + (row0 + row) * 256;
    int rx = (row & 15) << 4;
    #pragma unroll
    for (int c = 0; c < 8; ++c) {
      int col = c * 16 + ln;
      *(ushort*)(rbase + (((col >> 3) << 4) ^ rx) + (col & 7) * 2)
          = f2bf(v[c] * rinv);
    }
  }
}

// -------------------------------------------------------------------------
// attn: block = 64 q x 2048 p (1024 blocks, 4 waves). WAVE OWNS 16 P-ROWS x
// ALL 64 Q: per tile only 4 ds_read_b128 (own p-strip), 16 MFMAs with 16
// persistent Q frags. Swizzle slot^(row&15) (4-way max). Reg-staged double
// buffer, BAR = lgkmcnt(0)+s_barrier. Fixed softmax max = 1.0.
// -------------------------------------------------------------------------
static __device__ __forceinline__ v8bf ldfrag(const char* base, int row, int slot) {
  int byte = row * 256 + (((slot ^ (row & 15))) << 4);
  return __builtin_bit_cast(v8bf, *(const u32x4*)(base + byte));
}

#define STG_LOAD(R, j) do {                                                   \
  const char* _g = ctxb + (size_t)(P0 + (j) * 64) * 256 + w * 4096 + lane * 16;\
  R##0 = *(const u32x4*)(_g);        R##1 = *(const u32x4*)(_g + 1024);       \
  R##2 = *(const u32x4*)(_g + 2048); R##3 = *(const u32x4*)(_g + 3072);       \
} while (0)

#define STG_WRITE(R, buf) do {                                                \
  char* _l = (buf) + w * 4096 + lane * 16;                                    \
  *(u32x4*)(_l)        = R##0;  *(u32x4*)(_l + 1024) = R##1;                  \
  *(u32x4*)(_l + 2048) = R##2;  *(u32x4*)(_l + 3072) = R##3;                  \
} while (0)

// 4 A-frags (own p-strip) x 16 persistent Q frags -> 16 MFMAs
#define QKT(buf, acc) do {                                                    \
  v8bf _a[4];                                                                 \
  _Pragma("unroll")                                                           \
  for (int _k = 0; _k < 4; ++_k)                                              \
    _a[_k] = ldfrag(buf, w * 16 + ln, _k * 4 + g);                            \
  _Pragma("unroll")                                                           \
  for (int _t = 0; _t < 4; ++_t) {                                            \
    acc[_t] = (v4f){0.f, 0.f, 0.f, 0.f};                                      \
    _Pragma("unroll")                                                         \
    for (int _k = 0; _k < 4; ++_k)                                            \
      acc[_t] = MFMA(_a[_k], qf[_t][_k], acc[_t]);                            \
  }                                                                           \
} while (0)

#define LDB4(B, tj) do {                                                      \
  _Pragma("unroll")                                                           \
  for (int _t = 0; _t < 4; ++_t)                                              \
    B[_t] = btb[((size_t)(tj) * 2 + (w >> 1)) * 4096 + _t * 16];              \
} while (0)

#define EPIA(B) do {                                                          \
  _Pragma("unroll")                                                           \
  for (int _t = 0; _t < 4; ++_t) {                                            \
    uint32_t nib = (B[_t] >> bsh);                                            \
    _Pragma("unroll")                                                         \
    for (int _i = 0; _i < 4; ++_i) {                                          \
      float e = __expf(acc[_t][_i] - 1.0f);                                   \
      lsum[_t] += ((nib >> _i) & 1u) ? e : 0.f;                               \
    }                                                                         \
  }                                                                           \
} while (0)

#define EPIB(B, tj) do {                                                      \
  _Pragma("unroll")                                                           \
  for (int _t = 0; _t < 4; ++_t) {                                            \
    uint32_t nib = (B[_t] >> bsh);                                            \
    f32x4 o;                                                                  \
    _Pragma("unroll")                                                         \
    for (int _i = 0; _i < 4; ++_i)                                            \
      o[_i] = ((nib >> _i) & 1u) ? __expf(acc[_t][_i] - 1.0f) * lir[_t] : 0.f;\
    *(f32x4*)(obase + (size_t)_t * (16 * SEQ) + (tj) * 64) = o;               \
  }                                                                           \
} while (0)

#define BAR() do {                                                            \
  asm volatile("s_waitcnt lgkmcnt(0)" ::: "memory");                          \
  __builtin_amdgcn_s_barrier();                                               \
  __builtin_amdgcn_sched_barrier(0);                                          \
} while (0)

#define ATTN_COMMON                                                           \
  __shared__ __align__(16) char lds[33792];                                   \
  char* B0 = lds;                                                             \
  char* B1 = lds + 16384;                                                     \
  float* lW = (float*)(lds + 32768);   /* [4][64] */                          \
  const int t    = threadIdx.x;                                               \
  const int b    = blockIdx.x & 7;                                            \
  const int rest = blockIdx.x >> 3;                                           \
  const int ph   = rest & 1;                                                  \
  const int qg   = rest >> 1;                                                 \
  const int w    = t >> 6, lane = t & 63;                                     \
  const int ln   = lane & 15, g = lane >> 4;                                  \
  const int q0   = qg * 64;                                                   \
  const int P0   = ph * PH;                                                   \
  const int bsh  = (w & 1) * 16 + g * 4;                                      \
  const char* ctxb = (const char*)ctx + (size_t)b * SEQ * 256;                \
  const uint32_t* __restrict__ btb =                                          \
      bitsT + ((size_t)b * 128 + (P0 >> 5)) * 4096 + q0 + ln;                 \
  v8bf qf[4][4];                                                              \
  _Pragma("unroll")                                                           \
  for (int _t = 0; _t < 4; ++_t) {                                            \
    int qrow = q0 + _t * 16 + ln;                                             \
    _Pragma("unroll")                                                         \
    for (int kk = 0; kk < 4; ++kk)                                            \
      qf[_t][kk] = *(const v8bf*)(ctxb + (size_t)qrow * 256 +                 \
                     (((kk * 4 + g) ^ (qrow & 15)) << 4));                    \
  }                                                                           \
  u32x4 sA0, sA1, sA2, sA3, sB0, sB1, sB2, sB3;                               \
  uint32_t bc[4], bn[4];

__global__ __launch_bounds__(256) void attnA_kernel(
    const ushort* __restrict__ ctx, const uint32_t* __restrict__ bitsT,
    float* __restrict__ lpart)
{
  ATTN_COMMON
  float lsum[4] = {0.f, 0.f, 0.f, 0.f};

  STG_LOAD(sA, 0);
  STG_WRITE(sA, B0);
  STG_LOAD(sB, 1);
  LDB4(bc, 0);
  __syncthreads();

  for (int jj = 0; jj < NT; jj += 2) {
    if (jj + 1 < NT) LDB4(bn, jj + 1);
    if (jj + 2 < NT) STG_LOAD(sA, jj + 2);
    { v4f acc[4]; QKT(B0, acc); STG_WRITE(sB, B1); EPIA(bc); }
    BAR();
    #pragma unroll
    for (int _t = 0; _t < 4; ++_t) bc[_t] = bn[_t];

    if (jj + 2 < NT) LDB4(bn, jj + 2);
    if (jj + 3 < NT) STG_LOAD(sB, jj + 3);
    { v4f acc[4]; QKT(B1, acc); if (jj + 2 < NT) STG_WRITE(sA, B0); EPIA(bc); }
    BAR();
    #pragma unroll
    for (int _t = 0; _t < 4; ++_t) bc[_t] = bn[_t];
  }

  // reduce over g (p within strip), then across the 4 waves (p-strips)
  #pragma unroll
  for (int _t = 0; _t < 4; ++_t) {
    lsum[_t] += __shfl_xor(lsum[_t], 16, 64);
    lsum[_t] += __shfl_xor(lsum[_t], 32, 64);
  }
  if (g == 0) {
    #pragma unroll
    for (int _t = 0; _t < 4; ++_t) lW[w * 64 + _t * 16 + ln] = lsum[_t];
  }
  __syncthreads();
  if (t < 64) {
    float lf = lW[t] + lW[64 + t] + lW[128 + t] + lW[192 + t];
    lpart[(size_t)ph * (BATCH * SEQ) + (size_t)b * SEQ + q0 + t] = lf;
  }
}

__global__ __launch_bounds__(256) void attnB_kernel(
    const ushort* __restrict__ ctx, const uint32_t* __restrict__ bitsT,
    const float* __restrict__ lpart, float* __restrict__ out)
{
  ATTN_COMMON
  (void)lW;
  float lir[4];
  #pragma unroll
  for (int _t = 0; _t < 4; ++_t) {
    size_t grow = (size_t)b * SEQ + q0 + _t * 16 + ln;
    float lf = lpart[grow] + lpart[(size_t)(BATCH * SEQ) + grow];
    lir[_t] = (lf > 0.f) ? (1.f / lf) : 0.f;
  }
  float* __restrict__ obase =
      out + ((size_t)b * SEQ + q0 + ln) * SEQ + P0 + w * 16 + g * 4;

  STG_LOAD(sA, 0);
  STG_WRITE(sA, B0);
  STG_LOAD(sB, 1);
  LDB4(bc, 0);
  __syncthreads();

  for (int jj = 0; jj < NT; jj += 2) {
    if (jj + 1 < NT) LDB4(bn, jj + 1);
    if (jj + 2 < NT) STG_LOAD(sA, jj + 2);
    { v4f acc[4]; QKT(B0, acc); STG_WRITE(sB, B1); EPIB(bc, jj); }
    BAR();
    #pragma unroll
    for (int _t = 0; _t < 4; ++_t) bc[_t] = bn[_t];

    if (jj + 2 < NT) LDB4(bn, jj + 2);
    if (jj + 3 < NT) STG_LOAD(sB, jj + 3);
    { v4f acc[4]; QKT(B1, acc); if (jj + 2 < NT) STG_WRITE(sA, B0); EPIB(bc, jj + 1); }
    BAR();
    #pragma unroll
    for (int _t = 0; _t < 4; ++_t) bc[_t] = bn[_t];
  }
}

// -------------------------------------------------------------------------
extern "C" void kernel_launch(void* const* d_in, const int* in_sizes, int n_in,
                              void* d_out, int out_size, void* d_ws, size_t ws_size,
                              hipStream_t stream) {
  const float* query = (const float*)d_in[0];
  const int*   mask  = (const int*)d_in[1];
  const float* w_q   = (const float*)d_in[2];
  const float* b_q   = (const float*)d_in[3];
  const float* wt    = (const float*)d_in[4];
  float* out = (float*)d_out;

  ushort*   ctx   = (ushort*)d_ws;                               // 8 MB @0
  ushort*   whi   = (ushort*)((char*)d_ws + (8u << 20));         // 128 KB
  ushort*   wlo   = (ushort*)((char*)d_ws + (8u << 20) + (128u << 10));
  uint32_t* bitsT = (uint32_t*)((char*)d_ws + (9u << 20));       // 16.78 MB
  float*    lpart = (float*)((char*)d_ws + (26u << 20));         // 256 KB

  wsplit_kernel<<<dim3(64),   dim3(256), 0, stream>>>(w_q, whi, wlo);
  prep_kernel  <<<dim3(1024), dim3(256), 0, stream>>>(query, b_q, wt, mask,
                                                      whi, wlo, ctx, bitsT);
  attnA_kernel <<<dim3(1024), dim3(256), 0, stream>>>(ctx, bitsT, lpart);
  attnB_kernel <<<dim3(1024), dim3(256), 0, stream>>>(ctx, bitsT, lpart, out);
}